// Round 10
// baseline (582.624 us; speedup 1.0000x reference)
//
#include <hip/hip_runtime.h>

// ---------------------------------------------------------------------------
// BERT layer (attn + top-1 MoE FFN) for MI355X / gfx950.
// B=16 S=512 H=1024 I=4096 NH=16 DH=64 E=8.  bf16 MFMA (16x16x32), fp32 accum.
// R10: gemm_bt m201-style, race-free: BN=256, 512 thr (8 waves 2Mx4N),
// wave M-mapping mi*32+wr*16 so phase p reads exactly A stage-round p for all
// waves; 2 LDS buffers, stage units = row-ranges (full-row swizzle stays
// valid); per-phase counted vmcnt (derived ledger, never 0 mid-loop); one
// barrier per phase.  BM=256 for QKV/up, BM=128 for O/down.
// ---------------------------------------------------------------------------

typedef __attribute__((ext_vector_type(4))) float f32x4;
typedef __attribute__((ext_vector_type(8))) short s8v;   // 8 x bf16 bits
typedef __attribute__((ext_vector_type(4))) short s4v;   // 4 x bf16 bits
typedef unsigned short u16;

#define DEV static __device__ __forceinline__

DEV u16 f2bf(float f){
  union { float f; unsigned u; } v; v.f = f;
  unsigned r = v.u + 0x7fffu + ((v.u >> 16) & 1u);   // RNE
  return (u16)(r >> 16);
}

DEV f32x4 mfma16(s8v a, s8v b, f32x4 c){
  return __builtin_amdgcn_mfma_f32_16x16x32_bf16(a, b, c, 0, 0, 0);
}

DEV float wave_sum(float s){
#pragma unroll
  for (int o = 1; o < 64; o <<= 1) s += __shfl_xor(s, o);
  return s;
}

#define ASYNC_COPY16(g, l) \
  __builtin_amdgcn_global_load_lds((const __attribute__((address_space(1))) void*)(g), \
                                   (__attribute__((address_space(3))) void*)(l), 16, 0, 0)

// ---------------------------------------------------------------------------
// fp32 [n*8] -> bf16
__global__ __launch_bounds__(256) void cvt_bf16(const float* __restrict__ in,
                                                u16* __restrict__ out)
{
  const size_t i = ((size_t)blockIdx.x * 256 + threadIdx.x) * 8;
  f32x4 a = *(const f32x4*)&in[i];
  f32x4 b = *(const f32x4*)&in[i + 4];
  s8v o;
#pragma unroll
  for (int j = 0; j < 4; ++j){ o[j] = (short)f2bf(a[j]); o[4 + j] = (short)f2bf(b[j]); }
  *(s8v*)&out[i] = o;
}

// fp32 [R][C] -> bf16 [C][R]   (batched via blockIdx.z, stride R*C)
__global__ __launch_bounds__(256) void transpose_w(const float* __restrict__ in,
                                                   u16* __restrict__ out, int R, int C)
{
  __shared__ float t[64][65];
  const size_t bs = (size_t)blockIdx.z * R * (size_t)C;
  in += bs; out += bs;
  const int c0 = blockIdx.x * 64, r0 = blockIdx.y * 64;
  const int tx = threadIdx.x & 63, ty = threadIdx.x >> 6;   // 64 x 4
#pragma unroll
  for (int j = 0; j < 64; j += 4) t[ty + j][tx] = in[(size_t)(r0 + ty + j) * C + c0 + tx];
  __syncthreads();
#pragma unroll
  for (int j = 0; j < 64; j += 4) out[(size_t)(c0 + ty + j) * R + r0 + tx] = f2bf(t[tx][ty + j]);
}

// ---------------------------------------------------------------------------
// C = A[M,K](bf16) * Bt[N,K]^T(bf16) + bias.
// BN=256, 512 thr = 8 waves (2M x 4N).  Wave M-mapping: acc row mi lives at
// global rows mi*32 + wr*16 (+l15) -> phase p (mi = 2p,2p+1) reads rows
// [p*64, p*64+64) = exactly A stage-round p, for EVERY wave.
// 2 LDS buffers; tile t in buf t&1; stage units (row-ranges of 64 rows):
// issue order B0,B1,B2,B3,A0..A_{JA-1}.  Per-phase counted vmcnt ledger:
//   BM=128 (2 phases): ph0 vmcnt(1) [needs B0-3+A0, leaves A1]; stages B0-2'.
//                      ph1 vmcnt(3) [drains A1];       stages B3',A0',A1'.
//   BM=256 (4 phases): ph0 v(3) stages B0-1'; ph1 v(4) stages B2-3';
//                      ph2 v(5) stages A0-1'; ph3 v(6) stages A2-3'.
// Tail tile: no staging; waits 1,0 / 3,2,1,0.
// Swizzle: stored[row][seg] = global[row][seg ^ (row&7)] (16B segs, 128B rows;
// measured 0 conflicts in R6/R8).  nk = K/64 even >= 4 (K=1024/4096 ok).
// MODE 1: gelu->bf16   2: fp32 + residual   4: fused QKV (q|k|vt-scatter).
// SWZ: bijective XCD swizzle (requires nwg % 8 == 0).
template<int BM, int MODE, bool SWZ>
__global__ __launch_bounds__(512, 2) void gemm_bt(
    const u16* __restrict__ A, const u16* __restrict__ Bt,
    const float* __restrict__ bias, void* __restrict__ outp,
    const float* __restrict__ resid, int M, int N, int K,
    const int* __restrict__ choice,
    long aBatch, long outBatch, long residBatch, long btExpert, long biasExpert,
    void* __restrict__ out2, void* __restrict__ out3)
{
  constexpr int MI = BM / 32;      // acc rows: 8 or 4
  constexpr int JA = BM / 64;      // A stage rounds: 4 or 2

  int bx, by, bz;
  if (SWZ){
    const int nx = gridDim.x, ny = gridDim.y;
    const int nwg = nx * ny * gridDim.z;
    int id = blockIdx.x + nx * (blockIdx.y + ny * blockIdx.z);
    if ((nwg & 7) == 0){ const int q = nwg >> 3; id = (id & 7) * q + (id >> 3); }
    bx = id % nx; const int r2 = id / nx; by = r2 % ny; bz = r2 / ny;
  } else {
    bx = blockIdx.x; by = blockIdx.y; bz = blockIdx.z;
  }
  const int z = bz;
  if (choice){
    const int e = choice[z];
    Bt   += (size_t)e * btExpert;
    bias += (size_t)e * biasExpert;
  }
  A += (size_t)z * aBatch;

  const int tid = threadIdx.x;
  const int lane = tid & 63, wid = tid >> 6;     // 8 waves
  const int hi = lane >> 4, l15 = lane & 15;
  const int wr = wid >> 2, wc = wid & 3;         // 2M x 4N
  const int keyv = l15 & 7;
  const long row0 = (long)bx * BM;
  const long col0 = (long)by * 256;

  __shared__ __align__(16) u16 lA[2][BM * 64];   // 64 or 32 KB
  __shared__ __align__(16) u16 lB[2][256 * 64];  // 64 KB

  f32x4 acc[MI][4];
#pragma unroll
  for (int i = 0; i < MI; ++i)
#pragma unroll
    for (int j = 0; j < 4; ++j) acc[i][j] = f32x4{0.f, 0.f, 0.f, 0.f};

  // staging round j: row = j*64 + (tid>>3), seg = tid&7; src col pre-XORed.
  const int srow = tid >> 3;
  const int scol = (((tid & 7) ^ (srow & 7)) << 3);
  const u16* pA[4]; const u16* pB[4];
#pragma unroll
  for (int j = 0; j < JA; ++j) pA[j] = A  + (row0 + j * 64 + srow) * (size_t)K + scol;
#pragma unroll
  for (int j = 0; j < 4; ++j)  pB[j] = Bt + (col0 + j * 64 + srow) * (size_t)K + scol;

#define STGA(S_, J_) ASYNC_COPY16(pA[J_], &lA[S_][((J_) * 512 + tid) * 8])
#define STGB(S_, J_) ASYNC_COPY16(pB[J_], &lB[S_][((J_) * 512 + tid) * 8])
#define STG_ADV() do { \
  _Pragma("unroll") \
  for (int j = 0; j < JA; ++j) pA[j] += 64; \
  _Pragma("unroll") \
  for (int j = 0; j < 4; ++j)  pB[j] += 64; \
} while (0)

  s8v fb[4][2];                    // B frags, loaded at ph0, held per tile

// one phase: counted wait -> barrier -> ds_read (fb at ph0; af pair) ||
// stage next-tile units -> lgkm(0) -> 16 MFMA.  VMS_ literal per ledger.
#define PH(B_, P_, VMS_, ...) do { \
  asm volatile("s_waitcnt vmcnt(" VMS_ ")" ::: "memory"); \
  __builtin_amdgcn_s_barrier(); \
  __builtin_amdgcn_sched_barrier(0); \
  if ((P_) == 0){ \
    _Pragma("unroll") \
    for (int ni = 0; ni < 4; ++ni) \
      _Pragma("unroll") \
      for (int ks = 0; ks < 2; ++ks) \
        fb[ni][ks] = *(const s8v*)&lB[B_][(wc * 64 + ni * 16 + l15) * 64 \
                                          + (((ks * 4 + hi) ^ keyv) << 3)]; \
  } \
  s8v af[2][2]; \
  _Pragma("unroll") \
  for (int i = 0; i < 2; ++i) \
    _Pragma("unroll") \
    for (int ks = 0; ks < 2; ++ks) \
      af[i][ks] = *(const s8v*)&lA[B_][((2 * (P_) + i) * 32 + wr * 16 + l15) * 64 \
                                        + (((ks * 4 + hi) ^ keyv) << 3)]; \
  __VA_ARGS__ \
  asm volatile("s_waitcnt lgkmcnt(0)" ::: "memory"); \
  __builtin_amdgcn_sched_barrier(0); \
  __builtin_amdgcn_s_setprio(1); \
  _Pragma("unroll") \
  for (int i = 0; i < 2; ++i) \
    _Pragma("unroll") \
    for (int ni = 0; ni < 4; ++ni) \
      acc[2 * (P_) + i][ni] = mfma16(af[i][1], fb[ni][1], \
                              mfma16(af[i][0], fb[ni][0], acc[2 * (P_) + i][ni])); \
  __builtin_amdgcn_s_setprio(0); \
} while (0)

  const int nk = K >> 6;           // 16 or 64 (even, >= 4)
  // prologue: tile 0 -> buf0, unit order B0..B3, A0..A_{JA-1}
  STGB(0, 0); STGB(0, 1); STGB(0, 2); STGB(0, 3);
#pragma unroll
  for (int j = 0; j < JA; ++j) STGA(0, j);
  STG_ADV();

  if constexpr (BM == 128){
    for (int t = 0; t + 2 < nk; t += 2){
      PH(0, 0, "1", STGB(1, 0); STGB(1, 1); STGB(1, 2););
      PH(0, 1, "3", STGB(1, 3); STGA(1, 0); STGA(1, 1); STG_ADV(););
      PH(1, 0, "1", STGB(0, 0); STGB(0, 1); STGB(0, 2););
      PH(1, 1, "3", STGB(0, 3); STGA(0, 0); STGA(0, 1); STG_ADV(););
    }
    PH(0, 0, "1", STGB(1, 0); STGB(1, 1); STGB(1, 2););
    PH(0, 1, "3", STGB(1, 3); STGA(1, 0); STGA(1, 1););
    PH(1, 0, "1", );
    PH(1, 1, "0", );
  } else {
    for (int t = 0; t + 2 < nk; t += 2){
      PH(0, 0, "3", STGB(1, 0); STGB(1, 1););
      PH(0, 1, "4", STGB(1, 2); STGB(1, 3););
      PH(0, 2, "5", STGA(1, 0); STGA(1, 1););
      PH(0, 3, "6", STGA(1, 2); STGA(1, 3); STG_ADV(););
      PH(1, 0, "3", STGB(0, 0); STGB(0, 1););
      PH(1, 1, "4", STGB(0, 2); STGB(0, 3););
      PH(1, 2, "5", STGA(0, 0); STGA(0, 1););
      PH(1, 3, "6", STGA(0, 2); STGA(0, 3); STG_ADV(););
    }
    PH(0, 0, "3", STGB(1, 0); STGB(1, 1););
    PH(0, 1, "4", STGB(1, 2); STGB(1, 3););
    PH(0, 2, "5", STGA(1, 0); STGA(1, 1););
    PH(0, 3, "6", STGA(1, 2); STGA(1, 3););
    PH(1, 0, "3", );
    PH(1, 1, "2", );
    PH(1, 2, "1", );
    PH(1, 3, "0", );
  }
#undef PH
#undef STGA
#undef STGB
#undef STG_ADV

#pragma unroll
  for (int mi = 0; mi < MI; ++mi){
    const long rowb = row0 + mi * 32 + wr * 16 + hi * 4;
#pragma unroll
    for (int ni = 0; ni < 4; ++ni){
      const long col = col0 + wc * 64 + ni * 16 + l15;
      const float bv = bias[col];
#pragma unroll
      for (int r = 0; r < 4; ++r){
        const long row = rowb + r;
        float v = acc[mi][ni][r] + bv;
        if (MODE == 2){
          float* o = (float*)outp + (size_t)z * outBatch;
          const float* rs = resid + (size_t)z * residBatch;
          o[row * N + col] = v + rs[row * N + col];
        } else if (MODE == 1){
          u16* o = (u16*)outp + (size_t)z * outBatch;
          const float gv = 0.5f * v * (1.0f + erff(v * 0.70710678118654752f));
          o[row * N + col] = f2bf(gv);
        } else if (MODE == 4){          // fused QKV
          const int seg = (int)(col >> 10), lc = (int)(col & 1023);
          const u16 bv16 = f2bf(v);
          if (seg == 0)      ((u16*)outp)[row * 1024 + lc] = bv16;
          else if (seg == 1) ((u16*)out2)[row * 1024 + lc] = bv16;
          else {
            const int bb = (int)(row >> 9), ss = (int)(row & 511);
            const int hh = lc >> 6, dd = lc & 63;
            ((u16*)out3)[(((size_t)(bb * 16 + hh)) * 64 + dd) * 512 + ss] = bv16;
          }
        }
      }
    }
  }
}

// ---------------------------------------------------------------------------
// Flash attention, swapped form (S^T = K*Q^T; softmax state lane-local, q=l15).
// Block = (b, h, 128 q rows).  4 waves x 2 q-tiles (ILP-2 softmax chains).
__global__ __launch_bounds__(256) void attn_fwd(
    const u16* __restrict__ qb, const u16* __restrict__ kb,
    const u16* __restrict__ vt, u16* __restrict__ ctx)
{
  const int tid = threadIdx.x;
  const int lane = tid & 63, wid = tid >> 6;
  const int hi = lane >> 4, l15 = lane & 15;
  const int h = blockIdx.y, b = blockIdx.z;
  const int q0 = blockIdx.x * 128 + wid * 32;

  const u16* kp0 = kb + (size_t)b * 512 * 1024 + h * 64;     // K rows, stride 1024
  const u16* vp0 = vt + ((size_t)(b * 16 + h)) * 64 * 512;   // V^T rows, stride 512

  __shared__ __align__(16) u16 lK[2][64 * 64];
  __shared__ __align__(16) u16 lV[2][64 * 64];
  __shared__ __align__(16) u16 lP[4][2][16][72];

#define STAGE(bsel, k0s) do { \
  _Pragma("unroll") \
  for (int i = 0; i < 2; ++i){ \
    const int idx = i * 256 + tid; \
    const int row = idx >> 3, seg = idx & 7; \
    const int sc = ((seg ^ (row & 7)) << 3); \
    ASYNC_COPY16(kp0 + (size_t)((k0s) + row) * 1024 + sc, &lK[bsel][idx * 8]); \
    ASYNC_COPY16(vp0 + (size_t)row * 512 + (k0s) + sc,    &lV[bsel][idx * 8]); \
  } \
} while (0)

  const u16* qp = qb + ((size_t)b * 512 + q0) * 1024 + h * 64;
  s8v qf[2][2];
#pragma unroll
  for (int qt = 0; qt < 2; ++qt)
#pragma unroll
    for (int st = 0; st < 2; ++st)
      qf[qt][st] = *(const s8v*)&qp[(size_t)(qt * 16 + l15) * 1024 + st * 32 + hi * 8];

  f32x4 o[2][4];
#pragma unroll
  for (int qt = 0; qt < 2; ++qt)
#pragma unroll
    for (int mi = 0; mi < 4; ++mi) o[qt][mi] = f32x4{0.f, 0.f, 0.f, 0.f};
  float mrun[2] = {-3e38f, -3e38f}, lrun[2] = {0.f, 0.f};

  STAGE(0, 0);
  __syncthreads();

  for (int t = 0; t < 8; ++t){
    const int buf = t & 1;
    if (t < 7) STAGE(buf ^ 1, (t + 1) * 64);

    f32x4 s[2][4];
#pragma unroll
    for (int qt = 0; qt < 2; ++qt)
#pragma unroll
      for (int kt = 0; kt < 4; ++kt) s[qt][kt] = f32x4{0.f, 0.f, 0.f, 0.f};
#pragma unroll
    for (int st = 0; st < 2; ++st){
      s8v kf[4];
#pragma unroll
      for (int kt = 0; kt < 4; ++kt){
        const int row = kt * 16 + l15;
        kf[kt] = *(const s8v*)&lK[buf][row * 64 + (((st * 4 + hi) ^ (row & 7)) << 3)];
      }
#pragma unroll
      for (int qt = 0; qt < 2; ++qt)
#pragma unroll
        for (int kt = 0; kt < 4; ++kt)
          s[qt][kt] = mfma16(kf[kt], qf[qt][st], s[qt][kt]);
    }

#pragma unroll
    for (int qt = 0; qt < 2; ++qt){
      float mx = s[qt][0][0];
#pragma unroll
      for (int kt = 0; kt < 4; ++kt)
#pragma unroll
        for (int r = 0; r < 4; ++r) mx = fmaxf(mx, s[qt][kt][r]);
      mx *= 0.125f;
      mx = fmaxf(mx, __shfl_xor(mx, 16));
      mx = fmaxf(mx, __shfl_xor(mx, 32));
      const float mnew = fmaxf(mrun[qt], mx);
      const float alpha = __expf(mrun[qt] - mnew);
      mrun[qt] = mnew;
      float ps = 0.f;
#pragma unroll
      for (int kt = 0; kt < 4; ++kt){
        s4v pk;
#pragma unroll
        for (int r = 0; r < 4; ++r){
          const float p = __expf(s[qt][kt][r] * 0.125f - mnew);
          ps += p; pk[r] = (short)f2bf(p);
        }
        *(s4v*)&lP[wid][qt][l15][kt * 16 + 4 * hi] = pk;
      }
      ps += __shfl_xor(ps, 16);
      ps += __shfl_xor(ps, 32);
      lrun[qt] = lrun[qt] * alpha + ps;
#pragma unroll
      for (int mi = 0; mi < 4; ++mi)
#pragma unroll
        for (int r = 0; r < 4; ++r) o[qt][mi][r] *= alpha;
    }

#pragma unroll
    for (int ks = 0; ks < 2; ++ks){
      s8v vf[4];
#pragma unroll
      for (int mi = 0; mi < 4; ++mi){
        const int row = mi * 16 + l15;
        vf[mi] = *(const s8v*)&lV[buf][row * 64 + (((ks * 4 + hi) ^ (row & 7)) << 3)];
      }
#pragma unroll
      for (int qt = 0; qt < 2; ++qt){
        const s8v pf = *(const s8v*)&lP[wid][qt][l15][ks * 32 + 8 * hi];
#pragma unroll
        for (int mi = 0; mi < 4; ++mi)
          o[qt][mi] = mfma16(vf[mi], pf, o[qt][mi]);
      }
    }
    __syncthreads();
  }
#undef STAGE

#pragma unroll
  for (int qt = 0; qt < 2; ++qt){
    const float inv = 1.f / lrun[qt];
    u16* cp = ctx + ((size_t)b * 512 + q0 + qt * 16 + l15) * 1024 + h * 64;
#pragma unroll
    for (int mi = 0; mi < 4; ++mi)
#pragma unroll
      for (int r = 0; r < 4; ++r)
        cp[mi * 16 + 4 * hi + r] = f2bf(o[qt][mi][r] * inv);
  }
}

// ---------------------------------------------------------------------------
// Fused LN1 (in place, fp32) + LN2 -> bf16 xln + router column sums.
__global__ __launch_bounds__(256, 2) void ln12_colsum(
    float* __restrict__ t, const float* __restrict__ g1, const float* __restrict__ b1,
    const float* __restrict__ g2, const float* __restrict__ b2,
    u16* __restrict__ xln, float* __restrict__ colsum)
{
  const int b = blockIdx.y;
  const int wid = threadIdx.x >> 6, lane = threadIdx.x & 63;
  __shared__ float cacc[1024];
  for (int i = threadIdx.x; i < 1024; i += 256) cacc[i] = 0.f;
  __syncthreads();
  float acc[16];
#pragma unroll
  for (int i = 0; i < 16; ++i) acc[i] = 0.f;
  const int rbase = b * 512 + blockIdx.x * 64 + wid * 16;
  for (int rr = 0; rr < 16; ++rr){
    float* p = t + (size_t)(rbase + rr) * 1024;
    f32x4 v[4];
#pragma unroll
    for (int c = 0; c < 4; ++c) v[c] = *(const f32x4*)&p[c * 256 + lane * 4];
    float s = 0.f;
#pragma unroll
    for (int c = 0; c < 4; ++c) s += v[c][0] + v[c][1] + v[c][2] + v[c][3];
    const float mu = wave_sum(s) * (1.f / 1024.f);
    float s2 = 0.f;
#pragma unroll
    for (int c = 0; c < 4; ++c)
#pragma unroll
      for (int j = 0; j < 4; ++j){ const float d = v[c][j] - mu; s2 += d * d; }
    const float rs = rsqrtf(wave_sum(s2) * (1.f / 1024.f) + 1e-12f);
    float y1s = 0.f;
#pragma unroll
    for (int c = 0; c < 4; ++c){
      const f32x4 gg = *(const f32x4*)&g1[c * 256 + lane * 4];
      const f32x4 bb = *(const f32x4*)&b1[c * 256 + lane * 4];
#pragma unroll
      for (int j = 0; j < 4; ++j){
        v[c][j] = (v[c][j] - mu) * rs * gg[j] + bb[j];
        y1s += v[c][j];
      }
      *(f32x4*)&p[c * 256 + lane * 4] = v[c];      // attn_out (resid for down)
    }
    const float mu2 = wave_sum(y1s) * (1.f / 1024.f);
    float s22 = 0.f;
#pragma unroll
    for (int c = 0; c < 4; ++c)
#pragma unroll
      for (int j = 0; j < 4; ++j){ const float d = v[c][j] - mu2; s22 += d * d; }
    const float rs2 = rsqrtf(wave_sum(s22) * (1.f / 1024.f) + 1e-12f);
    u16* op = xln + (size_t)(rbase + rr) * 1024;
#pragma unroll
    for (int c = 0; c < 4; ++c){
      const f32x4 gg = *(const f32x4*)&g2[c * 256 + lane * 4];
      const f32x4 bb = *(const f32x4*)&b2[c * 256 + lane * 4];
      s4v ov;
#pragma unroll
      for (int j = 0; j < 4; ++j){
        const float y = (v[c][j] - mu2) * rs2 * gg[j] + bb[j];
        acc[c * 4 + j] += y;
        ov[j] = (short)f2bf(y);
      }
      *(s4v*)&op[c * 256 + lane * 4] = ov;
    }
  }
#pragma unroll
  for (int c = 0; c < 4; ++c)
#pragma unroll
    for (int j = 0; j < 4; ++j)
      atomicAdd(&cacc[c * 256 + lane * 4 + j], acc[c * 4 + j]);
  __syncthreads();
  for (int i = threadIdx.x; i < 1024; i += 256) atomicAdd(&colsum[b * 1024 + i], cacc[i]);
}

// logits[b][e] = (1/S) * sum_h colsum[b][h]*gate[h][e]; argmax -> choice.
__global__ void router_argmax(const float* __restrict__ colsum, const float* __restrict__ gate,
                              float* __restrict__ logits, int* __restrict__ choice)
{
  const int b = blockIdx.x, lane = threadIdx.x;   // 64 threads
  float pa[8];
#pragma unroll
  for (int e = 0; e < 8; ++e) pa[e] = 0.f;
  for (int it = 0; it < 16; ++it){
    const int hh = it * 64 + lane;
    const float c = colsum[b * 1024 + hh];
    const float* gp = gate + (size_t)hh * 8;
#pragma unroll
    for (int e = 0; e < 8; ++e) pa[e] += c * gp[e];
  }
#pragma unroll
  for (int e = 0; e < 8; ++e) pa[e] = wave_sum(pa[e]);
  if (lane == 0){
    float best = -3e38f; int bi = 0;
#pragma unroll
    for (int e = 0; e < 8; ++e){
      const float lg = pa[e] * (1.f / 512.f);
      logits[b * 8 + e] = lg;
      if (lg > best){ best = lg; bi = e; }   // strict > keeps first max (jnp.argmax)
    }
    choice[b] = bi;
  }
}

// ---------------------------------------------------------------------------
extern "C" void kernel_launch(void* const* d_in, const int* in_sizes, int n_in,
                              void* d_out, int out_size, void* d_ws, size_t ws_size,
                              hipStream_t stream)
{
  const float* x    = (const float*)d_in[0];
  const float* Wq   = (const float*)d_in[1];
  const float* bq   = (const float*)d_in[2];
  const float* Wk   = (const float*)d_in[3];
  const float* bk   = (const float*)d_in[4];
  const float* Wv   = (const float*)d_in[5];
  const float* bv   = (const float*)d_in[6];
  const float* Wo   = (const float*)d_in[7];
  const float* bo   = (const float*)d_in[8];
  const float* ln1g = (const float*)d_in[9];
  const float* ln1b = (const float*)d_in[10];
  const float* ln2g = (const float*)d_in[11];
  const float* ln2b = (const float*)d_in[12];
  const float* gate = (const float*)d_in[13];
  const float* Wup  = (const float*)d_in[14];
  const float* bup  = (const float*)d_in[15];
  const float* Wdn  = (const float*)d_in[16];
  const float* bdn  = (const float*)d_in[17];

  size_t off = 0;
  char* wsb = (char*)d_ws;
  auto take = [&](size_t n) -> void* {
    void* p = wsb + off; off += (n + 255) & ~(size_t)255; return p;
  };
  u16*   x_bf  = (u16*)take(8192ull * 1024 * 2);          // later: ctx
  u16*   Wqt   = (u16*)take(1024ull * 1024 * 2);          // Wqt/Wkt/Wvt contiguous
  u16*   Wkt   = (u16*)take(1024ull * 1024 * 2);
  u16*   Wvt   = (u16*)take(1024ull * 1024 * 2);
  u16*   Wot   = (u16*)take(1024ull * 1024 * 2);
  u16*   q_bf  = (u16*)take(8192ull * 1024 * 2);          // later: x_ln
  u16*   k_bf  = (u16*)take(8192ull * 1024 * 2);
  u16*   vt_bf = (u16*)take(8192ull * 1024 * 2);
  float* tmp   = (float*)take(8192ull * 1024 * 4);        // pre-LN1 -> attn_out
  u16*   Wupt  = (u16*)take(8ull * 4096 * 1024 * 2);
  u16*   Wdnt  = (u16*)take(8ull * 1024 * 4096 * 2);
  u16*   h_bf  = (u16*)take(8192ull * 4096 * 2);
  float* colsum = (float*)take(16ull * 1024 * 4);
  int*   choice = (int*)take(256);
  float* qkvb  = (float*)take(3072 * 4);                  // concat bq|bk|bv

  u16* ctx = x_bf;     // x_bf dead after QKV GEMM
  u16* xln = q_bf;     // q_bf dead after attention
  float* logits = (float*)d_out + 8388608;

  // 1. convert + transpose (+ bias concat for fused QKV)
  cvt_bf16<<<4096, 256, 0, stream>>>(x, x_bf);
  transpose_w<<<dim3(16, 16, 1), 256, 0, stream>>>(Wq,  Wqt,  1024, 1024);
  transpose_w<<<dim3(16, 16, 1), 256, 0, stream>>>(Wk,  Wkt,  1024, 1024);
  transpose_w<<<dim3(16, 16, 1), 256, 0, stream>>>(Wv,  Wvt,  1024, 1024);
  transpose_w<<<dim3(16, 16, 1), 256, 0, stream>>>(Wo,  Wot,  1024, 1024);
  transpose_w<<<dim3(64, 16, 8), 256, 0, stream>>>(Wup, Wupt, 1024, 4096);
  transpose_w<<<dim3(16, 64, 8), 256, 0, stream>>>(Wdn, Wdnt, 4096, 1024);
  hipMemcpyAsync(qkvb,        bq, 1024 * 4, hipMemcpyDeviceToDevice, stream);
  hipMemcpyAsync(qkvb + 1024, bk, 1024 * 4, hipMemcpyDeviceToDevice, stream);
  hipMemcpyAsync(qkvb + 2048, bv, 1024 * 4, hipMemcpyDeviceToDevice, stream);

  // 2. fused QKV projection (weights Wqt|Wkt|Wvt contiguous = [3072][1024])
  gemm_bt<256, 4, true><<<dim3(32, 12, 1), 512, 0, stream>>>(x_bf, Wqt, qkvb, q_bf,
      nullptr, 8192, 3072, 1024, nullptr, 0, 0, 0, 0, 0, k_bf, vt_bf);

  // 3. attention -> ctx (reuses x_bf)
  attn_fwd<<<dim3(4, 16, 16), 256, 0, stream>>>(q_bf, k_bf, vt_bf, ctx);

  // 4. output projection + residual(x) -> tmp (fp32), then fused LN1/LN2
  gemm_bt<128, 2, true><<<dim3(64, 4, 1), 512, 0, stream>>>(ctx, Wot, bo, tmp, x,
      8192, 1024, 1024, nullptr, 0, 0, 0, 0, 0, nullptr, nullptr);
  hipMemsetAsync(colsum, 0, 16 * 1024 * sizeof(float), stream);
  ln12_colsum<<<dim3(8, 16), 256, 0, stream>>>(tmp, ln1g, ln1b, ln2g, ln2b, xln, colsum);
  router_argmax<<<16, 64, 0, stream>>>(colsum, gate, logits, choice);

  // 5. MoE: up (gelu) then down (+attn_out residual) -> d_out
  gemm_bt<256, 1, true><<<dim3(2, 16, 16), 512, 0, stream>>>(xln, Wupt, bup, h_bf, nullptr,
      512, 4096, 1024, choice, 512ll * 1024, 512ll * 4096, 0, 4096ll * 1024, 4096,
      nullptr, nullptr);
  gemm_bt<128, 2, true><<<dim3(4, 4, 16), 512, 0, stream>>>(h_bf, Wdnt, bdn, d_out, tmp,
      512, 1024, 4096, choice, 512ll * 4096, 512ll * 1024, 512ll * 1024, 1024ll * 4096, 1024,
      nullptr, nullptr);
}

// Round 11
// 549.606 us; speedup vs baseline: 1.0601x; 1.0601x over previous
//
#include <hip/hip_runtime.h>

// ---------------------------------------------------------------------------
// BERT layer (attn + top-1 MoE FFN) for MI355X / gfx950.
// B=16 S=512 H=1024 I=4096 NH=16 DH=64 E=8.  bf16 MFMA (16x16x32), fp32 accum.
// R11: gemm_bt back to the R3 dbuf structure (128x128, BK=32, 32KB LDS) +
// R6 seg-swizzle (0 conflicts) + __launch_bounds__(256, 4): the six-schedule
// invariant was ~68 TF per resident wave; occupancy was self-capped at
// 2 blocks/CU by launch_bounds.  4 blocks/CU = 16 waves -> latency coverage.
// ---------------------------------------------------------------------------

typedef __attribute__((ext_vector_type(4))) float f32x4;
typedef __attribute__((ext_vector_type(8))) short s8v;   // 8 x bf16 bits
typedef __attribute__((ext_vector_type(4))) short s4v;   // 4 x bf16 bits
typedef unsigned short u16;

#define DEV static __device__ __forceinline__

DEV u16 f2bf(float f){
  union { float f; unsigned u; } v; v.f = f;
  unsigned r = v.u + 0x7fffu + ((v.u >> 16) & 1u);   // RNE
  return (u16)(r >> 16);
}

DEV f32x4 mfma16(s8v a, s8v b, f32x4 c){
  return __builtin_amdgcn_mfma_f32_16x16x32_bf16(a, b, c, 0, 0, 0);
}

DEV float wave_sum(float s){
#pragma unroll
  for (int o = 1; o < 64; o <<= 1) s += __shfl_xor(s, o);
  return s;
}

#define ASYNC_COPY16(g, l) \
  __builtin_amdgcn_global_load_lds((const __attribute__((address_space(1))) void*)(g), \
                                   (__attribute__((address_space(3))) void*)(l), 16, 0, 0)

// ---------------------------------------------------------------------------
// fp32 [n*8] -> bf16
__global__ __launch_bounds__(256) void cvt_bf16(const float* __restrict__ in,
                                                u16* __restrict__ out)
{
  const size_t i = ((size_t)blockIdx.x * 256 + threadIdx.x) * 8;
  f32x4 a = *(const f32x4*)&in[i];
  f32x4 b = *(const f32x4*)&in[i + 4];
  s8v o;
#pragma unroll
  for (int j = 0; j < 4; ++j){ o[j] = (short)f2bf(a[j]); o[4 + j] = (short)f2bf(b[j]); }
  *(s8v*)&out[i] = o;
}

// fp32 [R][C] -> bf16 [C][R]   (batched via blockIdx.z, stride R*C)
__global__ __launch_bounds__(256) void transpose_w(const float* __restrict__ in,
                                                   u16* __restrict__ out, int R, int C)
{
  __shared__ float t[64][65];
  const size_t bs = (size_t)blockIdx.z * R * (size_t)C;
  in += bs; out += bs;
  const int c0 = blockIdx.x * 64, r0 = blockIdx.y * 64;
  const int tx = threadIdx.x & 63, ty = threadIdx.x >> 6;   // 64 x 4
#pragma unroll
  for (int j = 0; j < 64; j += 4) t[ty + j][tx] = in[(size_t)(r0 + ty + j) * C + c0 + tx];
  __syncthreads();
#pragma unroll
  for (int j = 0; j < 64; j += 4) out[(size_t)(c0 + ty + j) * R + r0 + tx] = f2bf(t[tx][ty + j]);
}

// ---------------------------------------------------------------------------
// C = A[M,K](bf16) * Bt[N,K]^T(bf16) + bias;  128x128 tile, 4 waves, BK=32,
// double-buffered LDS (32KB) with prefetch overlap; 4 blocks/CU (16 waves).
// LDS seg-swizzle: stored[row][seg] = global[row][seg ^ ((row>>1)&3)] (16B
// segs; 64B rows wrap banks every 2 rows -> 2-way = free; measured 0 confl).
// MODE 1: gelu->bf16 out   2: fp32 out + residual
// MODE 4: fused QKV epilogue (cols 0-1023 -> outp, 1024-2047 -> out2,
//         2048-3071 -> vt-scatter to out3); bias is 3072-wide concat.
// SWZ: bijective XCD swizzle (requires nwg % 8 == 0; guarded).
template<int MODE, bool SWZ>
__global__ __launch_bounds__(256, 4) void gemm_bt(
    const u16* __restrict__ A, const u16* __restrict__ Bt,
    const float* __restrict__ bias, void* __restrict__ outp,
    const float* __restrict__ resid, int M, int N, int K,
    const int* __restrict__ choice,
    long aBatch, long outBatch, long residBatch, long btExpert, long biasExpert,
    void* __restrict__ out2, void* __restrict__ out3)
{
  int bx, by, bz;
  if (SWZ){
    const int nx = gridDim.x, ny = gridDim.y;
    const int nwg = nx * ny * gridDim.z;
    int id = blockIdx.x + nx * (blockIdx.y + ny * blockIdx.z);
    if ((nwg & 7) == 0){ const int q = nwg >> 3; id = (id & 7) * q + (id >> 3); }
    bx = id % nx; const int r2 = id / nx; by = r2 % ny; bz = r2 / ny;
  } else {
    bx = blockIdx.x; by = blockIdx.y; bz = blockIdx.z;
  }
  const int z = bz;
  if (choice){
    const int e = choice[z];
    Bt   += (size_t)e * btExpert;
    bias += (size_t)e * biasExpert;
  }
  A += (size_t)z * aBatch;

  const int tid = threadIdx.x;
  const int lane = tid & 63, wid = tid >> 6;
  const int hi = lane >> 4, l15 = lane & 15;
  const int wr = wid >> 1, wc = wid & 1;
  const long row0 = (long)bx * 128;
  const long col0 = (long)by * 128;

  __shared__ __align__(16) u16 lA[2][128 * 32];   // 16 KB
  __shared__ __align__(16) u16 lB[2][128 * 32];   // 16 KB

  f32x4 acc[4][4];
#pragma unroll
  for (int i = 0; i < 4; ++i)
#pragma unroll
    for (int j = 0; j < 4; ++j) acc[i][j] = f32x4{0.f, 0.f, 0.f, 0.f};

  // staging: each tile = 512 16B slots (2/thread); row = j*64 + (tid>>2),
  // seg = tid&3; swizzle key (row>>1)&3 = (tid>>3)&3 (j*64 doesn't affect it).
  const int r0 = tid >> 2;
  const int scol = (((tid & 3) ^ ((tid >> 3) & 3)) << 3);   // pre-swizzled src
  const u16* pA[2]; const u16* pB[2];
#pragma unroll
  for (int j = 0; j < 2; ++j){
    pA[j] = A  + (row0 + j * 64 + r0) * (size_t)K + scol;
    pB[j] = Bt + (col0 + j * 64 + r0) * (size_t)K + scol;
  }

#define GSTAGE(S_) do { \
  _Pragma("unroll") \
  for (int j = 0; j < 2; ++j) ASYNC_COPY16(pA[j], &lA[S_][(j * 256 + tid) * 8]); \
  _Pragma("unroll") \
  for (int j = 0; j < 2; ++j) ASYNC_COPY16(pB[j], &lB[S_][(j * 256 + tid) * 8]); \
  _Pragma("unroll") \
  for (int j = 0; j < 2; ++j){ pA[j] += 32; pB[j] += 32; } \
} while (0)

  // fragment bases (swizzled read): key = ((wr*64+mi*16+l15)>>1)&3 = (l15>>1)&3
  const int rkey = (l15 >> 1) & 3;
  const int baseA = (wr * 64 + l15) * 32 + ((hi ^ rkey) << 3);
  const int baseB = (wc * 64 + l15) * 32 + ((hi ^ rkey) << 3);

  const int nk = K >> 5;
  GSTAGE(0);
  __syncthreads();                      // vmcnt(0) drain: tile 0 ready

  for (int t = 0; t < nk; ++t){
    const int cur = t & 1;
    if (t + 1 < nk) GSTAGE(cur ^ 1);    // prefetch next tile

    s8v af[4], bfv[4];
#pragma unroll
    for (int mi = 0; mi < 4; ++mi)
      af[mi] = *(const s8v*)&lA[cur][baseA + mi * 512];
#pragma unroll
    for (int ni = 0; ni < 4; ++ni)
      bfv[ni] = *(const s8v*)&lB[cur][baseB + ni * 512];
#pragma unroll
    for (int mi = 0; mi < 4; ++mi)
#pragma unroll
      for (int ni = 0; ni < 4; ++ni)
        acc[mi][ni] = mfma16(af[mi], bfv[ni], acc[mi][ni]);
    __syncthreads();                    // one drain+barrier per K-step
  }
#undef GSTAGE

#pragma unroll
  for (int mi = 0; mi < 4; ++mi){
    const long rowb = row0 + wr * 64 + mi * 16 + hi * 4;
#pragma unroll
    for (int ni = 0; ni < 4; ++ni){
      const long col = col0 + wc * 64 + ni * 16 + l15;
      const float bv = bias[col];
#pragma unroll
      for (int r = 0; r < 4; ++r){
        const long row = rowb + r;
        float v = acc[mi][ni][r] + bv;
        if (MODE == 2){
          float* o = (float*)outp + (size_t)z * outBatch;
          const float* rs = resid + (size_t)z * residBatch;
          o[row * N + col] = v + rs[row * N + col];
        } else if (MODE == 1){
          u16* o = (u16*)outp + (size_t)z * outBatch;
          const float gv = 0.5f * v * (1.0f + erff(v * 0.70710678118654752f));
          o[row * N + col] = f2bf(gv);
        } else if (MODE == 4){          // fused QKV
          const int seg = (int)(col >> 10), lc = (int)(col & 1023);
          const u16 bv16 = f2bf(v);
          if (seg == 0)      ((u16*)outp)[row * 1024 + lc] = bv16;
          else if (seg == 1) ((u16*)out2)[row * 1024 + lc] = bv16;
          else {
            const int bb = (int)(row >> 9), ss = (int)(row & 511);
            const int hh = lc >> 6, dd = lc & 63;
            ((u16*)out3)[(((size_t)(bb * 16 + hh)) * 64 + dd) * 512 + ss] = bv16;
          }
        }
      }
    }
  }
}

// ---------------------------------------------------------------------------
// Flash attention, swapped form (S^T = K*Q^T; softmax state lane-local, q=l15).
// Block = (b, h, 128 q rows).  4 waves x 2 q-tiles (ILP-2 softmax chains).
__global__ __launch_bounds__(256) void attn_fwd(
    const u16* __restrict__ qb, const u16* __restrict__ kb,
    const u16* __restrict__ vt, u16* __restrict__ ctx)
{
  const int tid = threadIdx.x;
  const int lane = tid & 63, wid = tid >> 6;
  const int hi = lane >> 4, l15 = lane & 15;
  const int h = blockIdx.y, b = blockIdx.z;
  const int q0 = blockIdx.x * 128 + wid * 32;

  const u16* kp0 = kb + (size_t)b * 512 * 1024 + h * 64;     // K rows, stride 1024
  const u16* vp0 = vt + ((size_t)(b * 16 + h)) * 64 * 512;   // V^T rows, stride 512

  __shared__ __align__(16) u16 lK[2][64 * 64];
  __shared__ __align__(16) u16 lV[2][64 * 64];
  __shared__ __align__(16) u16 lP[4][2][16][72];

#define STAGE(bsel, k0s) do { \
  _Pragma("unroll") \
  for (int i = 0; i < 2; ++i){ \
    const int idx = i * 256 + tid; \
    const int row = idx >> 3, seg = idx & 7; \
    const int sc = ((seg ^ (row & 7)) << 3); \
    ASYNC_COPY16(kp0 + (size_t)((k0s) + row) * 1024 + sc, &lK[bsel][idx * 8]); \
    ASYNC_COPY16(vp0 + (size_t)row * 512 + (k0s) + sc,    &lV[bsel][idx * 8]); \
  } \
} while (0)

  const u16* qp = qb + ((size_t)b * 512 + q0) * 1024 + h * 64;
  s8v qf[2][2];
#pragma unroll
  for (int qt = 0; qt < 2; ++qt)
#pragma unroll
    for (int st = 0; st < 2; ++st)
      qf[qt][st] = *(const s8v*)&qp[(size_t)(qt * 16 + l15) * 1024 + st * 32 + hi * 8];

  f32x4 o[2][4];
#pragma unroll
  for (int qt = 0; qt < 2; ++qt)
#pragma unroll
    for (int mi = 0; mi < 4; ++mi) o[qt][mi] = f32x4{0.f, 0.f, 0.f, 0.f};
  float mrun[2] = {-3e38f, -3e38f}, lrun[2] = {0.f, 0.f};

  STAGE(0, 0);
  __syncthreads();

  for (int t = 0; t < 8; ++t){
    const int buf = t & 1;
    if (t < 7) STAGE(buf ^ 1, (t + 1) * 64);

    f32x4 s[2][4];
#pragma unroll
    for (int qt = 0; qt < 2; ++qt)
#pragma unroll
      for (int kt = 0; kt < 4; ++kt) s[qt][kt] = f32x4{0.f, 0.f, 0.f, 0.f};
#pragma unroll
    for (int st = 0; st < 2; ++st){
      s8v kf[4];
#pragma unroll
      for (int kt = 0; kt < 4; ++kt){
        const int row = kt * 16 + l15;
        kf[kt] = *(const s8v*)&lK[buf][row * 64 + (((st * 4 + hi) ^ (row & 7)) << 3)];
      }
#pragma unroll
      for (int qt = 0; qt < 2; ++qt)
#pragma unroll
        for (int kt = 0; kt < 4; ++kt)
          s[qt][kt] = mfma16(kf[kt], qf[qt][st], s[qt][kt]);
    }

#pragma unroll
    for (int qt = 0; qt < 2; ++qt){
      float mx = s[qt][0][0];
#pragma unroll
      for (int kt = 0; kt < 4; ++kt)
#pragma unroll
        for (int r = 0; r < 4; ++r) mx = fmaxf(mx, s[qt][kt][r]);
      mx *= 0.125f;
      mx = fmaxf(mx, __shfl_xor(mx, 16));
      mx = fmaxf(mx, __shfl_xor(mx, 32));
      const float mnew = fmaxf(mrun[qt], mx);
      const float alpha = __expf(mrun[qt] - mnew);
      mrun[qt] = mnew;
      float ps = 0.f;
#pragma unroll
      for (int kt = 0; kt < 4; ++kt){
        s4v pk;
#pragma unroll
        for (int r = 0; r < 4; ++r){
          const float p = __expf(s[qt][kt][r] * 0.125f - mnew);
          ps += p; pk[r] = (short)f2bf(p);
        }
        *(s4v*)&lP[wid][qt][l15][kt * 16 + 4 * hi] = pk;
      }
      ps += __shfl_xor(ps, 16);
      ps += __shfl_xor(ps, 32);
      lrun[qt] = lrun[qt] * alpha + ps;
#pragma unroll
      for (int mi = 0; mi < 4; ++mi)
#pragma unroll
        for (int r = 0; r < 4; ++r) o[qt][mi][r] *= alpha;
    }

#pragma unroll
    for (int ks = 0; ks < 2; ++ks){
      s8v vf[4];
#pragma unroll
      for (int mi = 0; mi < 4; ++mi){
        const int row = mi * 16 + l15;
        vf[mi] = *(const s8v*)&lV[buf][row * 64 + (((ks * 4 + hi) ^ (row & 7)) << 3)];
      }
#pragma unroll
      for (int qt = 0; qt < 2; ++qt){
        const s8v pf = *(const s8v*)&lP[wid][qt][l15][ks * 32 + 8 * hi];
#pragma unroll
        for (int mi = 0; mi < 4; ++mi)
          o[qt][mi] = mfma16(vf[mi], pf, o[qt][mi]);
      }
    }
    __syncthreads();
  }
#undef STAGE

#pragma unroll
  for (int qt = 0; qt < 2; ++qt){
    const float inv = 1.f / lrun[qt];
    u16* cp = ctx + ((size_t)b * 512 + q0 + qt * 16 + l15) * 1024 + h * 64;
#pragma unroll
    for (int mi = 0; mi < 4; ++mi)
#pragma unroll
      for (int r = 0; r < 4; ++r)
        cp[mi * 16 + 4 * hi + r] = f2bf(o[qt][mi][r] * inv);
  }
}

// ---------------------------------------------------------------------------
// Fused LN1 (in place, fp32) + LN2 -> bf16 xln + router column sums.
__global__ __launch_bounds__(256, 2) void ln12_colsum(
    float* __restrict__ t, const float* __restrict__ g1, const float* __restrict__ b1,
    const float* __restrict__ g2, const float* __restrict__ b2,
    u16* __restrict__ xln, float* __restrict__ colsum)
{
  const int b = blockIdx.y;
  const int wid = threadIdx.x >> 6, lane = threadIdx.x & 63;
  __shared__ float cacc[1024];
  for (int i = threadIdx.x; i < 1024; i += 256) cacc[i] = 0.f;
  __syncthreads();
  float acc[16];
#pragma unroll
  for (int i = 0; i < 16; ++i) acc[i] = 0.f;
  const int rbase = b * 512 + blockIdx.x * 64 + wid * 16;
  for (int rr = 0; rr < 16; ++rr){
    float* p = t + (size_t)(rbase + rr) * 1024;
    f32x4 v[4];
#pragma unroll
    for (int c = 0; c < 4; ++c) v[c] = *(const f32x4*)&p[c * 256 + lane * 4];
    float s = 0.f;
#pragma unroll
    for (int c = 0; c < 4; ++c) s += v[c][0] + v[c][1] + v[c][2] + v[c][3];
    const float mu = wave_sum(s) * (1.f / 1024.f);
    float s2 = 0.f;
#pragma unroll
    for (int c = 0; c < 4; ++c)
#pragma unroll
      for (int j = 0; j < 4; ++j){ const float d = v[c][j] - mu; s2 += d * d; }
    const float rs = rsqrtf(wave_sum(s2) * (1.f / 1024.f) + 1e-12f);
    float y1s = 0.f;
#pragma unroll
    for (int c = 0; c < 4; ++c){
      const f32x4 gg = *(const f32x4*)&g1[c * 256 + lane * 4];
      const f32x4 bb = *(const f32x4*)&b1[c * 256 + lane * 4];
#pragma unroll
      for (int j = 0; j < 4; ++j){
        v[c][j] = (v[c][j] - mu) * rs * gg[j] + bb[j];
        y1s += v[c][j];
      }
      *(f32x4*)&p[c * 256 + lane * 4] = v[c];      // attn_out (resid for down)
    }
    const float mu2 = wave_sum(y1s) * (1.f / 1024.f);
    float s22 = 0.f;
#pragma unroll
    for (int c = 0; c < 4; ++c)
#pragma unroll
      for (int j = 0; j < 4; ++j){ const float d = v[c][j] - mu2; s22 += d * d; }
    const float rs2 = rsqrtf(wave_sum(s22) * (1.f / 1024.f) + 1e-12f);
    u16* op = xln + (size_t)(rbase + rr) * 1024;
#pragma unroll
    for (int c = 0; c < 4; ++c){
      const f32x4 gg = *(const f32x4*)&g2[c * 256 + lane * 4];
      const f32x4 bb = *(const f32x4*)&b2[c * 256 + lane * 4];
      s4v ov;
#pragma unroll
      for (int j = 0; j < 4; ++j){
        const float y = (v[c][j] - mu2) * rs2 * gg[j] + bb[j];
        acc[c * 4 + j] += y;
        ov[j] = (short)f2bf(y);
      }
      *(s4v*)&op[c * 256 + lane * 4] = ov;
    }
  }
#pragma unroll
  for (int c = 0; c < 4; ++c)
#pragma unroll
    for (int j = 0; j < 4; ++j)
      atomicAdd(&cacc[c * 256 + lane * 4 + j], acc[c * 4 + j]);
  __syncthreads();
  for (int i = threadIdx.x; i < 1024; i += 256) atomicAdd(&colsum[b * 1024 + i], cacc[i]);
}

// logits[b][e] = (1/S) * sum_h colsum[b][h]*gate[h][e]; argmax -> choice.
__global__ void router_argmax(const float* __restrict__ colsum, const float* __restrict__ gate,
                              float* __restrict__ logits, int* __restrict__ choice)
{
  const int b = blockIdx.x, lane = threadIdx.x;   // 64 threads
  float pa[8];
#pragma unroll
  for (int e = 0; e < 8; ++e) pa[e] = 0.f;
  for (int it = 0; it < 16; ++it){
    const int hh = it * 64 + lane;
    const float c = colsum[b * 1024 + hh];
    const float* gp = gate + (size_t)hh * 8;
#pragma unroll
    for (int e = 0; e < 8; ++e) pa[e] += c * gp[e];
  }
#pragma unroll
  for (int e = 0; e < 8; ++e) pa[e] = wave_sum(pa[e]);
  if (lane == 0){
    float best = -3e38f; int bi = 0;
#pragma unroll
    for (int e = 0; e < 8; ++e){
      const float lg = pa[e] * (1.f / 512.f);
      logits[b * 8 + e] = lg;
      if (lg > best){ best = lg; bi = e; }   // strict > keeps first max (jnp.argmax)
    }
    choice[b] = bi;
  }
}

// ---------------------------------------------------------------------------
extern "C" void kernel_launch(void* const* d_in, const int* in_sizes, int n_in,
                              void* d_out, int out_size, void* d_ws, size_t ws_size,
                              hipStream_t stream)
{
  const float* x    = (const float*)d_in[0];
  const float* Wq   = (const float*)d_in[1];
  const float* bq   = (const float*)d_in[2];
  const float* Wk   = (const float*)d_in[3];
  const float* bk   = (const float*)d_in[4];
  const float* Wv   = (const float*)d_in[5];
  const float* bv   = (const float*)d_in[6];
  const float* Wo   = (const float*)d_in[7];
  const float* bo   = (const float*)d_in[8];
  const float* ln1g = (const float*)d_in[9];
  const float* ln1b = (const float*)d_in[10];
  const float* ln2g = (const float*)d_in[11];
  const float* ln2b = (const float*)d_in[12];
  const float* gate = (const float*)d_in[13];
  const float* Wup  = (const float*)d_in[14];
  const float* bup  = (const float*)d_in[15];
  const float* Wdn  = (const float*)d_in[16];
  const float* bdn  = (const float*)d_in[17];

  size_t off = 0;
  char* wsb = (char*)d_ws;
  auto take = [&](size_t n) -> void* {
    void* p = wsb + off; off += (n + 255) & ~(size_t)255; return p;
  };
  u16*   x_bf  = (u16*)take(8192ull * 1024 * 2);          // later: ctx
  u16*   Wqt   = (u16*)take(1024ull * 1024 * 2);          // Wqt/Wkt/Wvt contiguous
  u16*   Wkt   = (u16*)take(1024ull * 1024 * 2);
  u16*   Wvt   = (u16*)take(1024ull * 1024 * 2);
  u16*   Wot   = (u16*)take(1024ull * 1024 * 2);
  u16*   q_bf  = (u16*)take(8192ull * 1024 * 2);          // later: x_ln
  u16*   k_bf  = (u16*)take(8192ull * 1024 * 2);
  u16*   vt_bf = (u16*)take(8192ull * 1024 * 2);
  float* tmp   = (float*)take(8192ull * 1024 * 4);        // pre-LN1 -> attn_out
  u16*   Wupt  = (u16*)take(8ull * 4096 * 1024 * 2);
  u16*   Wdnt  = (u16*)take(8ull * 1024 * 4096 * 2);
  u16*   h_bf  = (u16*)take(8192ull * 4096 * 2);
  float* colsum = (float*)take(16ull * 1024 * 4);
  int*   choice = (int*)take(256);
  float* qkvb  = (float*)take(3072 * 4);                  // concat bq|bk|bv

  u16* ctx = x_bf;     // x_bf dead after QKV GEMM
  u16* xln = q_bf;     // q_bf dead after attention
  float* logits = (float*)d_out + 8388608;

  // 1. convert + transpose (+ bias concat for fused QKV)
  cvt_bf16<<<4096, 256, 0, stream>>>(x, x_bf);
  transpose_w<<<dim3(16, 16, 1), 256, 0, stream>>>(Wq,  Wqt,  1024, 1024);
  transpose_w<<<dim3(16, 16, 1), 256, 0, stream>>>(Wk,  Wkt,  1024, 1024);
  transpose_w<<<dim3(16, 16, 1), 256, 0, stream>>>(Wv,  Wvt,  1024, 1024);
  transpose_w<<<dim3(16, 16, 1), 256, 0, stream>>>(Wo,  Wot,  1024, 1024);
  transpose_w<<<dim3(64, 16, 8), 256, 0, stream>>>(Wup, Wupt, 1024, 4096);
  transpose_w<<<dim3(16, 64, 8), 256, 0, stream>>>(Wdn, Wdnt, 4096, 1024);
  hipMemcpyAsync(qkvb,        bq, 1024 * 4, hipMemcpyDeviceToDevice, stream);
  hipMemcpyAsync(qkvb + 1024, bk, 1024 * 4, hipMemcpyDeviceToDevice, stream);
  hipMemcpyAsync(qkvb + 2048, bv, 1024 * 4, hipMemcpyDeviceToDevice, stream);

  // 2. fused QKV projection (weights Wqt|Wkt|Wvt contiguous = [3072][1024])
  gemm_bt<4, true><<<dim3(64, 24, 1), 256, 0, stream>>>(x_bf, Wqt, qkvb, q_bf,
      nullptr, 8192, 3072, 1024, nullptr, 0, 0, 0, 0, 0, k_bf, vt_bf);

  // 3. attention -> ctx (reuses x_bf)
  attn_fwd<<<dim3(4, 16, 16), 256, 0, stream>>>(q_bf, k_bf, vt_bf, ctx);

  // 4. output projection + residual(x) -> tmp (fp32), then fused LN1/LN2
  gemm_bt<2, true><<<dim3(64, 8, 1), 256, 0, stream>>>(ctx, Wot, bo, tmp, x,
      8192, 1024, 1024, nullptr, 0, 0, 0, 0, 0, nullptr, nullptr);
  hipMemsetAsync(colsum, 0, 16 * 1024 * sizeof(float), stream);
  ln12_colsum<<<dim3(8, 16), 256, 0, stream>>>(tmp, ln1g, ln1b, ln2g, ln2b, xln, colsum);
  router_argmax<<<16, 64, 0, stream>>>(colsum, gate, logits, choice);

  // 5. MoE: up (gelu) then down (+attn_out residual) -> d_out
  gemm_bt<1, true><<<dim3(4, 32, 16), 256, 0, stream>>>(xln, Wupt, bup, h_bf, nullptr,
      512, 4096, 1024, choice, 512ll * 1024, 512ll * 4096, 0, 4096ll * 1024, 4096,
      nullptr, nullptr);
  gemm_bt<2, true><<<dim3(4, 8, 16), 256, 0, stream>>>(h_bf, Wdnt, bdn, d_out, tmp,
      512, 1024, 4096, choice, 512ll * 4096, 512ll * 1024, 512ll * 1024, 1024ll * 4096, 1024,
      nullptr, nullptr);
}